// Round 3
// baseline (227.159 us; speedup 1.0000x reference)
//
#include <hip/hip_runtime.h>
#include <hip/hip_bf16.h>

#define N_NODES 10000
#define KNEI    30
#define DIM     128
#define EDGES   (N_NODES * KNEI)

typedef __attribute__((ext_vector_type(4))) float  f32x4;
typedef __attribute__((ext_vector_type(8))) __bf16 bf16x8;
typedef __attribute__((ext_vector_type(4))) __bf16 bf16x4;

// packed bf16 weight offsets in d_ws (element units)
#define OFF_AW1 0        // 384x128 -> 12*8 tiles
#define OFF_AW2 49152    // 128x128 -> 4*8
#define OFF_NW1 67584    // 256x128 -> 8*8
#define OFF_NW2 100352   // 128x128
#define OFF_NW3 116736   // 128x128
#define OFF_TH  133120   // 128x128 (to_h_w)

// Pack W[k][n] (f32) into MFMA A-fragment order, bf16:
// tile = kt*Ntiles+nt ; lane holds n = nt*16+(lane&15), k = kt*32+(lane>>4)*8+i.
__global__ __launch_bounds__(256) void repack_w(const float* __restrict__ src,
                                                __bf16* __restrict__ dst,
                                                int Kd, int Nsrc, int Ntiles) {
    int t = blockIdx.x * 256 + threadIdx.x;
    int total = (Kd >> 5) * Ntiles * 512;
    if (t >= total) return;
    int i    = t & 7;
    int lane = (t >> 3) & 63;
    int tile = t >> 9;
    int nt = tile % Ntiles;
    int kt = tile / Ntiles;
    int k = kt * 32 + ((lane >> 4) << 3) + i;
    int n = nt * 16 + (lane & 15);
    float v = (n < Nsrc) ? src[k * Nsrc + n] : 0.f;
    dst[t] = (__bf16)v;
}

// fast gelu (tanh form; abs err ~2e-4, << bf16 noise)
__device__ __forceinline__ float gelu_f(float x) {
    float u = 0.7978845608f * (x + 0.044715f * x * x * x);
    float t = 1.f - 2.f / (__expf(2.f * u) + 1.f);
    return 0.5f * x * (1.f + t);
}

__device__ __forceinline__ bf16x4 cvt4(float4 v) {
    bf16x4 r;
    r[0] = (__bf16)v.x; r[1] = (__bf16)v.y; r[2] = (__bf16)v.z; r[3] = (__bf16)v.w;
    return r;
}

// LDS B-operand MFMA: 2 m-frags (32 rows), wave owns 16 n-features (nt = wv).
__device__ __forceinline__ void mm_lds(f32x4 acc[2], const __bf16* __restrict__ wfrag,
                                       const __bf16* x, int sx, int nkt,
                                       int wv, int lane) {
    const int mrow = lane & 15;
    const int kgrp = lane >> 4;
    for (int kt = 0; kt < nkt; ++kt) {
        bf16x8 a = *reinterpret_cast<const bf16x8*>(wfrag + ((kt * 8 + wv) * 64 + lane) * 8);
        const int kb = kt * 32 + kgrp * 8;
#pragma unroll
        for (int mf = 0; mf < 2; ++mf) {
            bf16x8 b = *reinterpret_cast<const bf16x8*>(x + (mf * 16 + mrow) * sx + kb);
            acc[mf] = __builtin_amdgcn_mfma_f32_16x16x32_bf16(a, b, acc[mf], 0, 0, 0);
        }
    }
}

// actmode: 0 = relu, 1 = gelu, 2 = none
__device__ __forceinline__ void store_act(f32x4 acc[2], const float* __restrict__ bias,
                                          __bf16* y, int sy, int actmode,
                                          int wv, int lane) {
    const int mrow = lane & 15;
    const int kgrp = lane >> 4;
    const int nb = wv * 16 + kgrp * 4;
    float b0 = bias[nb], b1 = bias[nb + 1], b2 = bias[nb + 2], b3 = bias[nb + 3];
#pragma unroll
    for (int mf = 0; mf < 2; ++mf) {
        bf16x4 pk;
        float vv[4] = {acc[mf][0] + b0, acc[mf][1] + b1, acc[mf][2] + b2, acc[mf][3] + b3};
#pragma unroll
        for (int r = 0; r < 4; ++r) {
            float v = vv[r];
            if (actmode == 0)      v = fmaxf(v, 0.f);
            else if (actmode == 1) v = gelu_f(v);
            pk[r] = (__bf16)v;
        }
        *reinterpret_cast<bf16x4*>(y + (mf * 16 + mrow) * sy + nb) = pk;
    }
}

#define ZERO2(A) do { A[0] = (f32x4){0.f,0.f,0.f,0.f}; A[1] = (f32x4){0.f,0.f,0.f,0.f}; } while (0)

// ---- kernel 1: fused MLPs + softmax + aggregation; writes pre[N][128] f32 to d_out ----
// One block = 1 node = 30 edges (padded to 32 rows). 8 waves; wave w owns n-features
// [w*16, w*16+16). mfma(A=weights, B=activations) so D-frag: lane&15 = edge row,
// (lane>>4)*4+r = feature. att layer-3 (128->4) fused into att layer-2 epilogue.
__global__ __launch_bounds__(512, 8) void gnn_fused(
    const float* __restrict__ h, const float* __restrict__ e, const int* __restrict__ eidx,
    const float* __restrict__ ab1, const float* __restrict__ ab2,
    const float* __restrict__ aw3, const float* __restrict__ ab3,
    const float* __restrict__ nb1, const float* __restrict__ nb2, const float* __restrict__ nb3,
    const __bf16* __restrict__ wp, float* __restrict__ pre_out) {

    __shared__ __bf16 S[32 * 264];      // [m][0:128)=e, [128:256)=hj (stride 264)
    __shared__ __bf16 Y1[32 * 136];     // att1-out, later node2-out
    __shared__ __bf16 Y2[32 * 136];     // node1-out, later V (node3-out)
    __shared__ float  sLogW[8][32][4];  // per-wave logit partials; [0]=final logits, [1]=softmax w
    __shared__ float  sPre[2][128];
    __shared__ int    sSrc[32];

    const int tid  = threadIdx.x;
    const int wv   = tid >> 6;
    const int lane = tid & 63;
    const int mrow = lane & 15;
    const int kgrp = lane >> 4;
    const int node = blockIdx.x;
    const long ebase = (long)node * KNEI;

    // ---- P0: stage e|hj (f32 -> bf16), pad rows 30/31 = 0; stage src idx ----
    if (tid < 32) sSrc[tid] = eidx[ebase + (tid < KNEI ? tid : 0)];
#pragma unroll
    for (int c = 0; c < 2; ++c) {
        int idx = c * 512 + tid;
        int m  = idx >> 5;   // row 0..31
        int jv = idx & 31;   // float4 col
        float4 ev = make_float4(0.f, 0.f, 0.f, 0.f), hjv = ev;
        if (m < KNEI) {
            long ge = ebase + m;
            ev  = *reinterpret_cast<const float4*>(e + ge * DIM + jv * 4);
            int dstn = eidx[EDGES + ge];
            hjv = *reinterpret_cast<const float4*>(h + (long)dstn * DIM + jv * 4);
        }
        *reinterpret_cast<bf16x4*>(&S[m * 264 + jv * 4])       = cvt4(ev);
        *reinterpret_cast<bf16x4*>(&S[m * 264 + 128 + jv * 4]) = cvt4(hjv);
    }
    __syncthreads();

    f32x4 acc[2];

    // ---- P1: att layer 1 (K=384): hi from global, e|hj from LDS -> relu -> Y1 ----
    ZERO2(acc);
    {
        const int s0 = sSrc[mrow], s1 = sSrc[16 + mrow];
#pragma unroll
        for (int kt = 0; kt < 4; ++kt) {   // hi part: k 0..127
            bf16x8 a = *reinterpret_cast<const bf16x8*>(wp + OFF_AW1 + ((kt * 8 + wv) * 64 + lane) * 8);
            const int ko = kt * 32 + kgrp * 8;
#pragma unroll
            for (int mf = 0; mf < 2; ++mf) {
                const float* hp = h + (long)(mf ? s1 : s0) * DIM + ko;
                float4 f0 = *reinterpret_cast<const float4*>(hp);
                float4 f1 = *reinterpret_cast<const float4*>(hp + 4);
                bf16x8 b;
                b[0] = (__bf16)f0.x; b[1] = (__bf16)f0.y; b[2] = (__bf16)f0.z; b[3] = (__bf16)f0.w;
                b[4] = (__bf16)f1.x; b[5] = (__bf16)f1.y; b[6] = (__bf16)f1.z; b[7] = (__bf16)f1.w;
                acc[mf] = __builtin_amdgcn_mfma_f32_16x16x32_bf16(a, b, acc[mf], 0, 0, 0);
            }
        }
    }
    mm_lds(acc, wp + OFF_AW1 + 4 * 8 * 512, S, 264, 8, wv, lane);  // k 128..383 (e|hj)
    store_act(acc, ab1, Y1, 136, 0, wv, lane);
    __syncthreads();

    // ---- P2: att layer 2 + fused logit layer; node layer 1 ----
    {
        ZERO2(acc);
        mm_lds(acc, wp + OFF_AW2, Y1, 136, 4, wv, lane);
        const int nb = wv * 16 + kgrp * 4;
        float b0 = ab2[nb], b1 = ab2[nb + 1], b2 = ab2[nb + 2], b3 = ab2[nb + 3];
        float4 w3v[4];
#pragma unroll
        for (int r = 0; r < 4; ++r)
            w3v[r] = *reinterpret_cast<const float4*>(aw3 + (nb + r) * 4);
        float lp[2][4];
#pragma unroll
        for (int mf = 0; mf < 2; ++mf) {
            lp[mf][0] = lp[mf][1] = lp[mf][2] = lp[mf][3] = 0.f;
            float vv[4] = {acc[mf][0] + b0, acc[mf][1] + b1, acc[mf][2] + b2, acc[mf][3] + b3};
#pragma unroll
            for (int r = 0; r < 4; ++r) {
                float v = fmaxf(vv[r], 0.f);
                lp[mf][0] += v * w3v[r].x;
                lp[mf][1] += v * w3v[r].y;
                lp[mf][2] += v * w3v[r].z;
                lp[mf][3] += v * w3v[r].w;
            }
        }
        // reduce over kgrp (lane ^16, ^32)
#pragma unroll
        for (int mf = 0; mf < 2; ++mf)
#pragma unroll
            for (int hh = 0; hh < 4; ++hh) {
                lp[mf][hh] += __shfl_xor(lp[mf][hh], 16);
                lp[mf][hh] += __shfl_xor(lp[mf][hh], 32);
            }
        if (kgrp == 0) {
#pragma unroll
            for (int mf = 0; mf < 2; ++mf) {
                float4 o = make_float4(lp[mf][0], lp[mf][1], lp[mf][2], lp[mf][3]);
                *reinterpret_cast<float4*>(&sLogW[wv][mf * 16 + mrow][0]) = o;
            }
        }
    }
    ZERO2(acc);
    mm_lds(acc, wp + OFF_NW1, S, 264, 8, wv, lane);   // node L1: [e|hj] K=256
    store_act(acc, nb1, Y2, 136, 1, wv, lane);
    __syncthreads();

    // ---- P3: logit cross-wave reduce; node layer 2 ----
    if (tid < 128) {
        int m = tid >> 2, hh = tid & 3;
        float s = ab3[hh];
#pragma unroll
        for (int w = 0; w < 8; ++w) s += sLogW[w][m][hh];
        sLogW[0][m][hh] = s * 0.17677669529f;   // /sqrt(32); final logits
    }
    ZERO2(acc);
    mm_lds(acc, wp + OFF_NW2, Y2, 136, 4, wv, lane);
    store_act(acc, nb2, Y1, 136, 1, wv, lane);
    __syncthreads();

    // ---- P4: node layer 3 -> V (Y2); softmax weights on 4 threads ----
    ZERO2(acc);
    mm_lds(acc, wp + OFF_NW3, Y1, 136, 4, wv, lane);
    store_act(acc, nb3, Y2, 136, 2, wv, lane);
    if (tid < 4) {
        float mx = -1e30f;
        for (int k = 0; k < KNEI; ++k) mx = fmaxf(mx, sLogW[0][k][tid]);
        float sum = 0.f;
        for (int k = 0; k < KNEI; ++k) sum += __expf(sLogW[0][k][tid] - mx);
        float inv = 1.f / sum;
        for (int k = 0; k < KNEI; ++k)
            sLogW[1][k][tid] = __expf(sLogW[0][k][tid] - mx) * inv;
    }
    __syncthreads();

    // ---- P5: softmax-weighted aggregation -> pre (f32, to d_out) ----
    if (tid < 256) {
        int ks = tid >> 7, dd = tid & 127, hh = dd >> 5;
        float a = 0.f;
#pragma unroll
        for (int kk = 0; kk < 15; ++kk) {
            int k = ks * 15 + kk;
            a += sLogW[1][k][hh] * (float)Y2[k * 136 + dd];
        }
        sPre[ks][dd] = a;
    }
    __syncthreads();
    if (tid < 128)
        pre_out[(long)node * DIM + tid] = sPre[0][tid] + sPre[1][tid];
}

// ---- kernel 2: out = pre @ to_h_w, in-place on d_out (64-row MFMA tiles) ----
__global__ __launch_bounds__(512) void proj_mm(float* __restrict__ io,
                                               const __bf16* __restrict__ wp) {
    __shared__ __bf16 sP[64 * 136];
    const int tid  = threadIdx.x;
    const int wv   = tid >> 6;
    const int lane = tid & 63;
    const int mrow = lane & 15;
    const int kgrp = lane >> 4;
    const int base = blockIdx.x * 64;

#pragma unroll
    for (int c = 0; c < 4; ++c) {
        int idx = c * 512 + tid;
        int m  = idx >> 5;
        int jv = idx & 31;
        int row = base + m;
        float4 v = make_float4(0.f, 0.f, 0.f, 0.f);
        if (row < N_NODES) v = *reinterpret_cast<const float4*>(io + (long)row * DIM + jv * 4);
        *reinterpret_cast<bf16x4*>(&sP[m * 136 + jv * 4]) = cvt4(v);
    }
    __syncthreads();

    f32x4 acc[4];
#pragma unroll
    for (int mf = 0; mf < 4; ++mf) acc[mf] = (f32x4){0.f, 0.f, 0.f, 0.f};
#pragma unroll
    for (int kt = 0; kt < 4; ++kt) {
        bf16x8 a = *reinterpret_cast<const bf16x8*>(wp + OFF_TH + ((kt * 8 + wv) * 64 + lane) * 8);
        const int kb = kt * 32 + kgrp * 8;
#pragma unroll
        for (int mf = 0; mf < 4; ++mf) {
            bf16x8 b = *reinterpret_cast<const bf16x8*>(sP + (mf * 16 + mrow) * 136 + kb);
            acc[mf] = __builtin_amdgcn_mfma_f32_16x16x32_bf16(a, b, acc[mf], 0, 0, 0);
        }
    }
    const int nb = wv * 16 + kgrp * 4;
#pragma unroll
    for (int mf = 0; mf < 4; ++mf) {
        int row = base + mf * 16 + mrow;
        if (row < N_NODES) {
            float4 o = make_float4(acc[mf][0], acc[mf][1], acc[mf][2], acc[mf][3]);
            *reinterpret_cast<float4*>(io + (long)row * DIM + nb) = o;
        }
    }
}

extern "C" void kernel_launch(void* const* d_in, const int* in_sizes, int n_in,
                              void* d_out, int out_size, void* d_ws, size_t ws_size,
                              hipStream_t stream) {
    const float* h   = (const float*)d_in[0];
    const float* e   = (const float*)d_in[1];
    const int*   ei  = (const int*)d_in[2];
    const float* aw1 = (const float*)d_in[3];
    const float* ab1 = (const float*)d_in[4];
    const float* aw2 = (const float*)d_in[5];
    const float* ab2 = (const float*)d_in[6];
    const float* aw3 = (const float*)d_in[7];
    const float* ab3 = (const float*)d_in[8];
    const float* nw1 = (const float*)d_in[9];
    const float* nb1 = (const float*)d_in[10];
    const float* nw2 = (const float*)d_in[11];
    const float* nb2 = (const float*)d_in[12];
    const float* nw3 = (const float*)d_in[13];
    const float* nb3 = (const float*)d_in[14];
    const float* thw = (const float*)d_in[15];
    float* out = (float*)d_out;
    __bf16* wp = (__bf16*)d_ws;

    // weight repack (f32 -> bf16 MFMA-fragment order), ~300 KB into d_ws
    repack_w<<<192, 256, 0, stream>>>(aw1, wp + OFF_AW1, 384, 128, 8);
    repack_w<<<64,  256, 0, stream>>>(aw2, wp + OFF_AW2, 128, 128, 8);
    repack_w<<<128, 256, 0, stream>>>(nw1, wp + OFF_NW1, 256, 128, 8);
    repack_w<<<64,  256, 0, stream>>>(nw2, wp + OFF_NW2, 128, 128, 8);
    repack_w<<<64,  256, 0, stream>>>(nw3, wp + OFF_NW3, 128, 128, 8);
    repack_w<<<64,  256, 0, stream>>>(thw, wp + OFF_TH,  128, 128, 8);

    gnn_fused<<<N_NODES, 512, 0, stream>>>(h, e, ei, ab1, ab2, aw3, ab3,
                                           nb1, nb2, nb3, wp, out);
    proj_mm<<<(N_NODES + 63) / 64, 512, 0, stream>>>(out, wp);
}

// Round 4
// 188.567 us; speedup vs baseline: 1.2047x; 1.2047x over previous
//
#include <hip/hip_runtime.h>
#include <hip/hip_bf16.h>

#define N_NODES 10000
#define KNEI    30
#define DIM     128
#define EDGES   (N_NODES * KNEI)

typedef __attribute__((ext_vector_type(4))) float  f32x4;
typedef __attribute__((ext_vector_type(8))) __bf16 bf16x8;
typedef __attribute__((ext_vector_type(4))) __bf16 bf16x4;

// packed bf16 weight offsets in d_ws (element units)
#define OFF_AW1 0        // 384x128 -> 12*8 tiles (kt 0..3 = hi part, 4..11 = e|hj)
#define OFF_AW2 49152    // 128x128 -> 4*8
#define OFF_NW1 67584    // 256x128 -> 8*8
#define OFF_NW2 100352   // 128x128
#define OFF_NW3 116736   // 128x128
#define OFF_TH  133120   // 128x128 (to_h_w)
#define YHI_BYTE_OFF (300 * 1024)   // f32 yhi[N][128] after weights

// Pack W[k][n] (f32) into MFMA A-fragment order, bf16:
// tile = kt*Ntiles+nt ; lane holds n = nt*16+(lane&15), k = kt*32+(lane>>4)*8+i.
__global__ __launch_bounds__(256) void repack_w(const float* __restrict__ src,
                                                __bf16* __restrict__ dst,
                                                int Kd, int Nsrc, int Ntiles) {
    int t = blockIdx.x * 256 + threadIdx.x;
    int total = (Kd >> 5) * Ntiles * 512;
    if (t >= total) return;
    int i    = t & 7;
    int lane = (t >> 3) & 63;
    int tile = t >> 9;
    int nt = tile % Ntiles;
    int kt = tile / Ntiles;
    int k = kt * 32 + ((lane >> 4) << 3) + i;
    int n = nt * 16 + (lane & 15);
    float v = (n < Nsrc) ? src[k * Nsrc + n] : 0.f;
    dst[t] = (__bf16)v;
}

// fast gelu (tanh form; abs err ~2e-4, << bf16 noise)
__device__ __forceinline__ float gelu_f(float x) {
    float u = 0.7978845608f * (x + 0.044715f * x * x * x);
    float t = 1.f - 2.f / (__expf(2.f * u) + 1.f);
    return 0.5f * x * (1.f + t);
}

__device__ __forceinline__ bf16x4 cvt4(float4 v) {
    bf16x4 r;
    r[0] = (__bf16)v.x; r[1] = (__bf16)v.y; r[2] = (__bf16)v.z; r[3] = (__bf16)v.w;
    return r;
}

// LDS B-operand MFMA: 2 m-frags (32 rows), wave owns 16 n-features (nt = wv).
__device__ __forceinline__ void mm_lds(f32x4 acc[2], const __bf16* __restrict__ wfrag,
                                       const __bf16* x, int sx, int nkt,
                                       int wv, int lane) {
    const int mrow = lane & 15;
    const int kgrp = lane >> 4;
#pragma unroll
    for (int kt = 0; kt < nkt; ++kt) {
        bf16x8 a = *reinterpret_cast<const bf16x8*>(wfrag + ((kt * 8 + wv) * 64 + lane) * 8);
        const int kb = kt * 32 + kgrp * 8;
#pragma unroll
        for (int mf = 0; mf < 2; ++mf) {
            bf16x8 b = *reinterpret_cast<const bf16x8*>(x + (mf * 16 + mrow) * sx + kb);
            acc[mf] = __builtin_amdgcn_mfma_f32_16x16x32_bf16(a, b, acc[mf], 0, 0, 0);
        }
    }
}

// actmode: 0 = relu, 1 = gelu, 2 = none. bias may be a per-node yhi row.
__device__ __forceinline__ void store_act(f32x4 acc[2], const float* __restrict__ bias,
                                          __bf16* y, int sy, int actmode,
                                          int wv, int lane) {
    const int mrow = lane & 15;
    const int kgrp = lane >> 4;
    const int nb = wv * 16 + kgrp * 4;
    float b0 = bias[nb], b1 = bias[nb + 1], b2 = bias[nb + 2], b3 = bias[nb + 3];
#pragma unroll
    for (int mf = 0; mf < 2; ++mf) {
        bf16x4 pk;
        float vv[4] = {acc[mf][0] + b0, acc[mf][1] + b1, acc[mf][2] + b2, acc[mf][3] + b3};
#pragma unroll
        for (int r = 0; r < 4; ++r) {
            float v = vv[r];
            if (actmode == 0)      v = fmaxf(v, 0.f);
            else if (actmode == 1) v = gelu_f(v);
            pk[r] = (__bf16)v;
        }
        *reinterpret_cast<bf16x4*>(y + (mf * 16 + mrow) * sy + nb) = pk;
    }
}

#define ZERO2(A) do { A[0] = (f32x4){0.f,0.f,0.f,0.f}; A[1] = (f32x4){0.f,0.f,0.f,0.f}; } while (0)

// ---- generic 128->128 row GEMM: out[m] = in[m] @ Wfrag (+bias); 64 rows/block ----
// used for yhi precompute (in=h, out=yhi, bias=ab1) and final proj (in=out=d_out).
__global__ __launch_bounds__(512) void mm128(const float* __restrict__ in,
                                             float* __restrict__ outp,
                                             const __bf16* __restrict__ wfrag,
                                             const float* __restrict__ bias) {
    __shared__ __bf16 sP[64 * 136];
    const int tid  = threadIdx.x;
    const int wv   = tid >> 6;
    const int lane = tid & 63;
    const int mrow = lane & 15;
    const int kgrp = lane >> 4;
    const int base = blockIdx.x * 64;

#pragma unroll
    for (int c = 0; c < 4; ++c) {
        int idx = c * 512 + tid;
        int m  = idx >> 5;
        int jv = idx & 31;
        int row = base + m;
        float4 v = make_float4(0.f, 0.f, 0.f, 0.f);
        if (row < N_NODES) v = *reinterpret_cast<const float4*>(in + (long)row * DIM + jv * 4);
        *reinterpret_cast<bf16x4*>(&sP[m * 136 + jv * 4]) = cvt4(v);
    }
    __syncthreads();

    f32x4 acc[4];
#pragma unroll
    for (int mf = 0; mf < 4; ++mf) acc[mf] = (f32x4){0.f, 0.f, 0.f, 0.f};
#pragma unroll
    for (int kt = 0; kt < 4; ++kt) {
        bf16x8 a = *reinterpret_cast<const bf16x8*>(wfrag + ((kt * 8 + wv) * 64 + lane) * 8);
        const int kb = kt * 32 + kgrp * 8;
#pragma unroll
        for (int mf = 0; mf < 4; ++mf) {
            bf16x8 b = *reinterpret_cast<const bf16x8*>(sP + (mf * 16 + mrow) * 136 + kb);
            acc[mf] = __builtin_amdgcn_mfma_f32_16x16x32_bf16(a, b, acc[mf], 0, 0, 0);
        }
    }
    const int nb = wv * 16 + kgrp * 4;
    float b0 = 0.f, b1 = 0.f, b2 = 0.f, b3 = 0.f;
    if (bias) { b0 = bias[nb]; b1 = bias[nb + 1]; b2 = bias[nb + 2]; b3 = bias[nb + 3]; }
#pragma unroll
    for (int mf = 0; mf < 4; ++mf) {
        int row = base + mf * 16 + mrow;
        if (row < N_NODES) {
            float4 o = make_float4(acc[mf][0] + b0, acc[mf][1] + b1,
                                   acc[mf][2] + b2, acc[mf][3] + b3);
            *reinterpret_cast<float4*>(outp + (long)row * DIM + nb) = o;
        }
    }
}

// ---- kernel 1: fused MLPs + softmax + aggregation; writes pre[N][128] f32 ----
// One block = 1 node = 30 edges (padded to 32 rows). 8 waves; wave w owns n-features
// [w*16, w*16+16). hi is block-constant (src=repeat(arange)), so its att-L1
// contribution is the precomputed per-node row yhi = h@W1hi + ab1, applied as bias.
__global__ __launch_bounds__(512, 4) void gnn_fused(
    const float* __restrict__ h, const float* __restrict__ e, const int* __restrict__ eidx,
    const float* __restrict__ yhi,
    const float* __restrict__ ab2, const float* __restrict__ aw3, const float* __restrict__ ab3,
    const float* __restrict__ nb1, const float* __restrict__ nb2, const float* __restrict__ nb3,
    const __bf16* __restrict__ wp, float* __restrict__ pre_out) {

    __shared__ __bf16 S[32 * 264];      // [m][0:128)=e, [128:256)=hj (stride 264)
    __shared__ __bf16 Y1[32 * 136];     // att1-out -> node2-out
    __shared__ __bf16 Y2[32 * 136];     // node1-out -> V (node3-out)
    __shared__ float  sLogW[8][32][4];  // per-wave logit partials; [0]=logits, [1]=softmax w
    __shared__ float  sPre[2][128];

    const int tid  = threadIdx.x;
    const int wv   = tid >> 6;
    const int lane = tid & 63;
    const int mrow = lane & 15;
    const int kgrp = lane >> 6 ? 0 : (lane >> 4);  // keep simple below
    const int kg   = lane >> 4;
    const int node = blockIdx.x;
    const long ebase = (long)node * KNEI;
    (void)kgrp;

    // ---- P0: stage e|hj (f32 -> bf16), pad rows 30/31 = 0 ----
#pragma unroll
    for (int c = 0; c < 2; ++c) {
        int idx = c * 512 + tid;
        int m  = idx >> 5;   // row 0..31
        int jv = idx & 31;   // float4 col
        float4 ev = make_float4(0.f, 0.f, 0.f, 0.f), hjv = ev;
        if (m < KNEI) {
            long ge = ebase + m;
            ev  = *reinterpret_cast<const float4*>(e + ge * DIM + jv * 4);
            int dstn = eidx[EDGES + ge];
            hjv = *reinterpret_cast<const float4*>(h + (long)dstn * DIM + jv * 4);
        }
        *reinterpret_cast<bf16x4*>(&S[m * 264 + jv * 4])       = cvt4(ev);
        *reinterpret_cast<bf16x4*>(&S[m * 264 + 128 + jv * 4]) = cvt4(hjv);
    }
    __syncthreads();

    f32x4 acc[2];

    // ---- P1: att layer 1: [e|hj] K=256 MFMA + yhi-as-bias -> relu -> Y1 ----
    ZERO2(acc);
    mm_lds(acc, wp + OFF_AW1 + 16384, S, 264, 8, wv, lane);
    store_act(acc, yhi + (long)node * DIM, Y1, 136, 0, wv, lane);
    __syncthreads();

    // ---- P2: att layer 2 + fused logit layer; node layer 1 ----
    {
        ZERO2(acc);
        mm_lds(acc, wp + OFF_AW2, Y1, 136, 4, wv, lane);
        const int nb = wv * 16 + kg * 4;
        float b0 = ab2[nb], b1 = ab2[nb + 1], b2 = ab2[nb + 2], b3 = ab2[nb + 3];
        float4 w3v[4];
#pragma unroll
        for (int r = 0; r < 4; ++r)
            w3v[r] = *reinterpret_cast<const float4*>(aw3 + (nb + r) * 4);
        float lp[2][4];
#pragma unroll
        for (int mf = 0; mf < 2; ++mf) {
            lp[mf][0] = lp[mf][1] = lp[mf][2] = lp[mf][3] = 0.f;
            float vv[4] = {acc[mf][0] + b0, acc[mf][1] + b1, acc[mf][2] + b2, acc[mf][3] + b3};
#pragma unroll
            for (int r = 0; r < 4; ++r) {
                float v = fmaxf(vv[r], 0.f);
                lp[mf][0] += v * w3v[r].x;
                lp[mf][1] += v * w3v[r].y;
                lp[mf][2] += v * w3v[r].z;
                lp[mf][3] += v * w3v[r].w;
            }
        }
#pragma unroll
        for (int mf = 0; mf < 2; ++mf)
#pragma unroll
            for (int hh = 0; hh < 4; ++hh) {
                lp[mf][hh] += __shfl_xor(lp[mf][hh], 16);
                lp[mf][hh] += __shfl_xor(lp[mf][hh], 32);
            }
        if (kg == 0) {
#pragma unroll
            for (int mf = 0; mf < 2; ++mf) {
                float4 o = make_float4(lp[mf][0], lp[mf][1], lp[mf][2], lp[mf][3]);
                *reinterpret_cast<float4*>(&sLogW[wv][mf * 16 + mrow][0]) = o;
            }
        }
    }
    ZERO2(acc);
    mm_lds(acc, wp + OFF_NW1, S, 264, 8, wv, lane);   // node L1: [e|hj] K=256
    store_act(acc, nb1, Y2, 136, 1, wv, lane);
    __syncthreads();

    // ---- P3: logit cross-wave reduce; node layer 2: Y2 -> Y1 ----
    if (tid < 128) {
        int m = tid >> 2, hh = tid & 3;
        float s = ab3[hh];
#pragma unroll
        for (int w = 0; w < 8; ++w) s += sLogW[w][m][hh];
        sLogW[0][m][hh] = s * 0.17677669529f;   // /sqrt(32)
    }
    ZERO2(acc);
    mm_lds(acc, wp + OFF_NW2, Y2, 136, 4, wv, lane);
    store_act(acc, nb2, Y1, 136, 1, wv, lane);
    __syncthreads();

    // ---- P4: node layer 3 -> V (Y2); softmax weights on 4 threads ----
    ZERO2(acc);
    mm_lds(acc, wp + OFF_NW3, Y1, 136, 4, wv, lane);
    store_act(acc, nb3, Y2, 136, 2, wv, lane);
    if (tid < 4) {
        float mx = -1e30f;
        for (int k = 0; k < KNEI; ++k) mx = fmaxf(mx, sLogW[0][k][tid]);
        float sum = 0.f;
        for (int k = 0; k < KNEI; ++k) sum += __expf(sLogW[0][k][tid] - mx);
        float inv = 1.f / sum;
        for (int k = 0; k < KNEI; ++k)
            sLogW[1][k][tid] = __expf(sLogW[0][k][tid] - mx) * inv;
    }
    __syncthreads();

    // ---- P5: softmax-weighted aggregation -> pre ----
    if (tid < 256) {
        int ks = tid >> 7, dd = tid & 127, hh = dd >> 5;
        float a = 0.f;
#pragma unroll
        for (int kk = 0; kk < 15; ++kk) {
            int k = ks * 15 + kk;
            a += sLogW[1][k][hh] * (float)Y2[k * 136 + dd];
        }
        sPre[ks][dd] = a;
    }
    __syncthreads();
    if (tid < 128)
        pre_out[(long)node * DIM + tid] = sPre[0][tid] + sPre[1][tid];
}

extern "C" void kernel_launch(void* const* d_in, const int* in_sizes, int n_in,
                              void* d_out, int out_size, void* d_ws, size_t ws_size,
                              hipStream_t stream) {
    const float* h   = (const float*)d_in[0];
    const float* e   = (const float*)d_in[1];
    const int*   ei  = (const int*)d_in[2];
    const float* aw1 = (const float*)d_in[3];
    const float* ab1 = (const float*)d_in[4];
    const float* aw2 = (const float*)d_in[5];
    const float* ab2 = (const float*)d_in[6];
    const float* aw3 = (const float*)d_in[7];
    const float* ab3 = (const float*)d_in[8];
    const float* nw1 = (const float*)d_in[9];
    const float* nb1 = (const float*)d_in[10];
    const float* nw2 = (const float*)d_in[11];
    const float* nb2 = (const float*)d_in[12];
    const float* nw3 = (const float*)d_in[13];
    const float* nb3 = (const float*)d_in[14];
    const float* thw = (const float*)d_in[15];
    float* out = (float*)d_out;
    __bf16* wp = (__bf16*)d_ws;
    float* yhi = (float*)((char*)d_ws + YHI_BYTE_OFF);

    // weight repack (f32 -> bf16 MFMA-fragment order), ~300 KB into d_ws
    repack_w<<<192, 256, 0, stream>>>(aw1, wp + OFF_AW1, 384, 128, 8);
    repack_w<<<64,  256, 0, stream>>>(aw2, wp + OFF_AW2, 128, 128, 8);
    repack_w<<<128, 256, 0, stream>>>(nw1, wp + OFF_NW1, 256, 128, 8);
    repack_w<<<64,  256, 0, stream>>>(nw2, wp + OFF_NW2, 128, 128, 8);
    repack_w<<<64,  256, 0, stream>>>(nw3, wp + OFF_NW3, 128, 128, 8);
    repack_w<<<64,  256, 0, stream>>>(thw, wp + OFF_TH,  128, 128, 8);

    const int nblk = (N_NODES + 63) / 64;
    // yhi = h @ att_w1[0:128,:] + ab1   (hi part of att layer 1, per node)
    mm128<<<nblk, 512, 0, stream>>>(h, yhi, wp + OFF_AW1, ab1);

    gnn_fused<<<N_NODES, 512, 0, stream>>>(h, e, ei, yhi, ab2, aw3, ab3,
                                           nb1, nb2, nb3, wp, out);
    // out = pre @ to_h_w (in-place)
    mm128<<<nblk, 512, 0, stream>>>(out, out, wp + OFF_TH, nullptr);
}

// Round 5
// 179.655 us; speedup vs baseline: 1.2644x; 1.0496x over previous
//
#include <hip/hip_runtime.h>
#include <hip/hip_bf16.h>

#define N_NODES 10000
#define KNEI    30
#define DIM     128
#define EDGES   (N_NODES * KNEI)

typedef __attribute__((ext_vector_type(4))) float  f32x4;
typedef __attribute__((ext_vector_type(8))) __bf16 bf16x8;
typedef __attribute__((ext_vector_type(4))) __bf16 bf16x4;

// packed bf16 weight offsets in d_ws (element units), contiguous tiles of 512
#define OFF_AW1 0        // 384x128: tiles   0..95  (kt0..3 = hi part)
#define OFF_AW2 49152    // 128x128: tiles  96..127
#define OFF_NW1 65536    // 256x128: tiles 128..191
#define OFF_NW2 98304    // 128x128: tiles 192..223
#define OFF_NW3 114688   // 128x128: tiles 224..255
#define OFF_TH  131072   // 128x128: tiles 256..287
#define TOT_TILES 288
#define YHI_BYTE_OFF (300 * 1024)   // f32 yhi[N][128] after weights

// Pack all six W[k][n] (f32) into MFMA A-fragment order, bf16, one launch.
// tile = kt*8+nt ; lane holds n = nt*16+(lane&15), k = kt*32+(lane>>4)*8+i.
__global__ __launch_bounds__(256) void repack_all(
    const float* __restrict__ aw1, const float* __restrict__ aw2,
    const float* __restrict__ nw1, const float* __restrict__ nw2,
    const float* __restrict__ nw3, const float* __restrict__ thw,
    __bf16* __restrict__ dst) {
    int t = blockIdx.x * 256 + threadIdx.x;
    if (t >= TOT_TILES * 512) return;
    int tile = t >> 9;
    const float* src; int lt;
    if      (tile < 96)  { src = aw1; lt = tile; }
    else if (tile < 128) { src = aw2; lt = tile - 96; }
    else if (tile < 192) { src = nw1; lt = tile - 128; }
    else if (tile < 224) { src = nw2; lt = tile - 192; }
    else if (tile < 256) { src = nw3; lt = tile - 224; }
    else                 { src = thw; lt = tile - 256; }
    int i    = t & 7;
    int lane = (t >> 3) & 63;
    int nt = lt & 7;
    int kt = lt >> 3;
    int k = kt * 32 + ((lane >> 4) << 3) + i;
    int n = nt * 16 + (lane & 15);
    dst[t] = (__bf16)src[k * DIM + n];
}

// fast gelu (tanh form; abs err ~2e-4, << bf16 noise)
__device__ __forceinline__ float gelu_f(float x) {
    float u = 0.7978845608f * (x + 0.044715f * x * x * x);
    float t = 1.f - 2.f / (__expf(2.f * u) + 1.f);
    return 0.5f * x * (1.f + t);
}

__device__ __forceinline__ bf16x4 cvt4(float4 v) {
    bf16x4 r;
    r[0] = (__bf16)v.x; r[1] = (__bf16)v.y; r[2] = (__bf16)v.z; r[3] = (__bf16)v.w;
    return r;
}

// 4-wave LDS-B MFMA: wave owns n-tiles {2wv, 2wv+1}; acc[nt][mf].
__device__ __forceinline__ void mm_lds4(f32x4 acc[2][2], const __bf16* __restrict__ wfrag,
                                        const __bf16* x, int sx, int nkt,
                                        int wv, int lane) {
    const int mrow = lane & 15;
    const int kgrp = lane >> 4;
#pragma unroll
    for (int kt = 0; kt < nkt; ++kt) {
        bf16x8 a0 = *reinterpret_cast<const bf16x8*>(wfrag + ((kt * 8 + wv * 2 + 0) * 64 + lane) * 8);
        bf16x8 a1 = *reinterpret_cast<const bf16x8*>(wfrag + ((kt * 8 + wv * 2 + 1) * 64 + lane) * 8);
        const int kb = kt * 32 + kgrp * 8;
        bf16x8 b0 = *reinterpret_cast<const bf16x8*>(x + mrow * sx + kb);
        bf16x8 b1 = *reinterpret_cast<const bf16x8*>(x + (16 + mrow) * sx + kb);
        acc[0][0] = __builtin_amdgcn_mfma_f32_16x16x32_bf16(a0, b0, acc[0][0], 0, 0, 0);
        acc[0][1] = __builtin_amdgcn_mfma_f32_16x16x32_bf16(a0, b1, acc[0][1], 0, 0, 0);
        acc[1][0] = __builtin_amdgcn_mfma_f32_16x16x32_bf16(a1, b0, acc[1][0], 0, 0, 0);
        acc[1][1] = __builtin_amdgcn_mfma_f32_16x16x32_bf16(a1, b1, acc[1][1], 0, 0, 0);
    }
}

// actmode: 0 = relu, 1 = gelu. bias may be a per-node yhi row.
__device__ __forceinline__ void store_act4(f32x4 acc[2][2], const float* __restrict__ bias,
                                           __bf16* y, int sy, int actmode,
                                           int wv, int lane) {
    const int mrow = lane & 15;
    const int kgrp = lane >> 4;
#pragma unroll
    for (int nt = 0; nt < 2; ++nt) {
        const int nb = wv * 32 + nt * 16 + kgrp * 4;
        float b0 = bias[nb], b1 = bias[nb + 1], b2 = bias[nb + 2], b3 = bias[nb + 3];
#pragma unroll
        for (int mf = 0; mf < 2; ++mf) {
            bf16x4 pk;
            float vv[4] = {acc[nt][mf][0] + b0, acc[nt][mf][1] + b1,
                           acc[nt][mf][2] + b2, acc[nt][mf][3] + b3};
#pragma unroll
            for (int r = 0; r < 4; ++r) {
                float v = vv[r];
                v = actmode == 0 ? fmaxf(v, 0.f) : gelu_f(v);
                pk[r] = (__bf16)v;
            }
            *reinterpret_cast<bf16x4*>(y + (mf * 16 + mrow) * sy + nb) = pk;
        }
    }
}

#define ZERO4(A) do { A[0][0]=(f32x4){0.f,0.f,0.f,0.f}; A[0][1]=(f32x4){0.f,0.f,0.f,0.f}; \
                      A[1][0]=(f32x4){0.f,0.f,0.f,0.f}; A[1][1]=(f32x4){0.f,0.f,0.f,0.f}; } while (0)

// ---- generic 128->128 row GEMM (64 rows/block, 8 waves): out = in @ Wfrag (+bias) ----
__global__ __launch_bounds__(512) void mm128(const float* __restrict__ in,
                                             float* __restrict__ outp,
                                             const __bf16* __restrict__ wfrag,
                                             const float* __restrict__ bias) {
    __shared__ __bf16 sP[64 * 136];
    const int tid  = threadIdx.x;
    const int wv   = tid >> 6;
    const int lane = tid & 63;
    const int mrow = lane & 15;
    const int kgrp = lane >> 4;
    const int base = blockIdx.x * 64;

#pragma unroll
    for (int c = 0; c < 4; ++c) {
        int idx = c * 512 + tid;
        int m  = idx >> 5;
        int jv = idx & 31;
        int row = base + m;
        float4 v = make_float4(0.f, 0.f, 0.f, 0.f);
        if (row < N_NODES) v = *reinterpret_cast<const float4*>(in + (long)row * DIM + jv * 4);
        *reinterpret_cast<bf16x4*>(&sP[m * 136 + jv * 4]) = cvt4(v);
    }
    __syncthreads();

    f32x4 acc[4];
#pragma unroll
    for (int mf = 0; mf < 4; ++mf) acc[mf] = (f32x4){0.f, 0.f, 0.f, 0.f};
#pragma unroll
    for (int kt = 0; kt < 4; ++kt) {
        bf16x8 a = *reinterpret_cast<const bf16x8*>(wfrag + ((kt * 8 + wv) * 64 + lane) * 8);
        const int kb = kt * 32 + kgrp * 8;
#pragma unroll
        for (int mf = 0; mf < 4; ++mf) {
            bf16x8 b = *reinterpret_cast<const bf16x8*>(sP + (mf * 16 + mrow) * 136 + kb);
            acc[mf] = __builtin_amdgcn_mfma_f32_16x16x32_bf16(a, b, acc[mf], 0, 0, 0);
        }
    }
    const int nb = wv * 16 + kgrp * 4;
    float b0 = 0.f, b1 = 0.f, b2 = 0.f, b3 = 0.f;
    if (bias) { b0 = bias[nb]; b1 = bias[nb + 1]; b2 = bias[nb + 2]; b3 = bias[nb + 3]; }
#pragma unroll
    for (int mf = 0; mf < 4; ++mf) {
        int row = base + mf * 16 + mrow;
        if (row < N_NODES) {
            float4 o = make_float4(acc[mf][0] + b0, acc[mf][1] + b1,
                                   acc[mf][2] + b2, acc[mf][3] + b3);
            *reinterpret_cast<float4*>(outp + (long)row * DIM + nb) = o;
        }
    }
}

// ---- kernel 1: fused MLPs + softmax + aggregation; writes pre[N][128] f32 ----
// One block = 1 node = 30 edges (padded to 32 rows). 4 waves; wave w owns features
// [w*32, w*32+32) = exactly head w. Aggregation fused into node-L3 epilogue via
// zero-padded softmax weights + shfl_xor butterfly over the 16 m-rows.
__global__ __launch_bounds__(256, 4) void gnn_fused(
    const float* __restrict__ h, const float* __restrict__ e, const int* __restrict__ eidx,
    const float* __restrict__ yhi,
    const float* __restrict__ ab2, const float* __restrict__ aw3, const float* __restrict__ ab3,
    const float* __restrict__ nb1, const float* __restrict__ nb2, const float* __restrict__ nb3,
    const __bf16* __restrict__ wp, float* __restrict__ pre_out) {

    __shared__ __bf16 S[32 * 264];      // [m][0:128)=e, [128:256)=hj (stride 264)
    __shared__ __bf16 Y1[32 * 136];     // att1-out -> node2-out
    __shared__ __bf16 Y2[32 * 136];     // node1-out
    __shared__ float  sLogW[4][32][4];  // per-wave logit partials; [0] = final logits
    __shared__ float  sW[32][4];        // softmax weights (rows 30/31 = 0)

    const int tid  = threadIdx.x;
    const int wv   = tid >> 6;
    const int lane = tid & 63;
    const int mrow = lane & 15;
    const int kg   = lane >> 4;
    const int node = blockIdx.x;
    const long ebase = (long)node * KNEI;

    // ---- P0: stage e|hj (f32 -> bf16), pad rows 30/31 = 0 ----
#pragma unroll
    for (int c = 0; c < 4; ++c) {
        int idx = c * 256 + tid;
        int m  = idx >> 5;   // row 0..31
        int jv = idx & 31;   // float4 col
        float4 ev = make_float4(0.f, 0.f, 0.f, 0.f), hjv = ev;
        if (m < KNEI) {
            long ge = ebase + m;
            ev  = *reinterpret_cast<const float4*>(e + ge * DIM + jv * 4);
            int dstn = eidx[EDGES + ge];
            hjv = *reinterpret_cast<const float4*>(h + (long)dstn * DIM + jv * 4);
        }
        *reinterpret_cast<bf16x4*>(&S[m * 264 + jv * 4])       = cvt4(ev);
        *reinterpret_cast<bf16x4*>(&S[m * 264 + 128 + jv * 4]) = cvt4(hjv);
    }
    __syncthreads();   // b0

    f32x4 acc[2][2];

    // ---- P1: att layer 1: [e|hj] K=256 MFMA + yhi-as-bias -> relu -> Y1 ----
    ZERO4(acc);
    mm_lds4(acc, wp + OFF_AW1 + 16384, S, 264, 8, wv, lane);
    store_act4(acc, yhi + (long)node * DIM, Y1, 136, 0, wv, lane);
    __syncthreads();   // b1

    // ---- P2: att layer 2 + fused logit layer (no act store); node layer 1 ----
    {
        ZERO4(acc);
        mm_lds4(acc, wp + OFF_AW2, Y1, 136, 4, wv, lane);
        float lp[2][4];
        lp[0][0]=lp[0][1]=lp[0][2]=lp[0][3]=0.f;
        lp[1][0]=lp[1][1]=lp[1][2]=lp[1][3]=0.f;
#pragma unroll
        for (int nt = 0; nt < 2; ++nt) {
            const int nb = wv * 32 + nt * 16 + kg * 4;
            float b0 = ab2[nb], b1 = ab2[nb + 1], b2 = ab2[nb + 2], b3 = ab2[nb + 3];
            float4 w3v[4];
#pragma unroll
            for (int r = 0; r < 4; ++r)
                w3v[r] = *reinterpret_cast<const float4*>(aw3 + (nb + r) * 4);
#pragma unroll
            for (int mf = 0; mf < 2; ++mf) {
                float vv[4] = {acc[nt][mf][0] + b0, acc[nt][mf][1] + b1,
                               acc[nt][mf][2] + b2, acc[nt][mf][3] + b3};
#pragma unroll
                for (int r = 0; r < 4; ++r) {
                    float v = fmaxf(vv[r], 0.f);
                    lp[mf][0] += v * w3v[r].x;
                    lp[mf][1] += v * w3v[r].y;
                    lp[mf][2] += v * w3v[r].z;
                    lp[mf][3] += v * w3v[r].w;
                }
            }
        }
#pragma unroll
        for (int mf = 0; mf < 2; ++mf)
#pragma unroll
            for (int hh = 0; hh < 4; ++hh) {
                lp[mf][hh] += __shfl_xor(lp[mf][hh], 16);
                lp[mf][hh] += __shfl_xor(lp[mf][hh], 32);
            }
        if (kg == 0) {
#pragma unroll
            for (int mf = 0; mf < 2; ++mf) {
                float4 o = make_float4(lp[mf][0], lp[mf][1], lp[mf][2], lp[mf][3]);
                *reinterpret_cast<float4*>(&sLogW[wv][mf * 16 + mrow][0]) = o;
            }
        }
    }
    ZERO4(acc);
    mm_lds4(acc, wp + OFF_NW1, S, 264, 8, wv, lane);   // node L1: [e|hj] K=256
    store_act4(acc, nb1, Y2, 136, 1, wv, lane);
    __syncthreads();   // b2

    // ---- P3: logit cross-wave reduce (128 thr); node layer 2: Y2 -> Y1 ----
    if (tid < 128) {
        int m = tid >> 2, hh = tid & 3;
        float s = ab3[hh];
#pragma unroll
        for (int w = 0; w < 4; ++w) s += sLogW[w][m][hh];
        sLogW[0][m][hh] = s * 0.17677669529f;   // /sqrt(32)
    }
    ZERO4(acc);
    mm_lds4(acc, wp + OFF_NW2, Y2, 136, 4, wv, lane);
    store_act4(acc, nb2, Y1, 136, 1, wv, lane);
    __syncthreads();   // b3

    // ---- P4: softmax weights (wave 0, lanes 0..31); node layer 3 MFMA ----
    if (wv == 0 && lane < 32) {
        float4 lg = (lane < KNEI) ? *reinterpret_cast<float4*>(&sLogW[0][lane][0])
                                  : make_float4(-1e30f, -1e30f, -1e30f, -1e30f);
        float4 mx = lg;
#pragma unroll
        for (int msk = 1; msk <= 16; msk <<= 1) {
            mx.x = fmaxf(mx.x, __shfl_xor(mx.x, msk));
            mx.y = fmaxf(mx.y, __shfl_xor(mx.y, msk));
            mx.z = fmaxf(mx.z, __shfl_xor(mx.z, msk));
            mx.w = fmaxf(mx.w, __shfl_xor(mx.w, msk));
        }
        float4 ex = make_float4(__expf(lg.x - mx.x), __expf(lg.y - mx.y),
                                __expf(lg.z - mx.z), __expf(lg.w - mx.w));
        float4 sm = ex;
#pragma unroll
        for (int msk = 1; msk <= 16; msk <<= 1) {
            sm.x += __shfl_xor(sm.x, msk);
            sm.y += __shfl_xor(sm.y, msk);
            sm.z += __shfl_xor(sm.z, msk);
            sm.w += __shfl_xor(sm.w, msk);
        }
        float4 w = make_float4(ex.x / sm.x, ex.y / sm.y, ex.z / sm.z, ex.w / sm.w);
        *reinterpret_cast<float4*>(&sW[lane][0]) = w;   // rows 30/31 -> 0
    }
    ZERO4(acc);
    mm_lds4(acc, wp + OFF_NW3, Y1, 136, 4, wv, lane);
    __syncthreads();   // b4: sW visible

    // ---- P5: fused aggregation epilogue: pre[n] = sum_m w[m]*(V + b) ----
    {
        float wgt0 = sW[mrow][wv];        // edge m = mrow      (mf=0)
        float wgt1 = sW[16 + mrow][wv];   // edge m = 16 + mrow (mf=1)
        float part[2][4];
#pragma unroll
        for (int nt = 0; nt < 2; ++nt)
#pragma unroll
            for (int r = 0; r < 4; ++r)
                part[nt][r] = wgt0 * acc[nt][0][r] + wgt1 * acc[nt][1][r];
#pragma unroll
        for (int msk = 1; msk <= 8; msk <<= 1)
#pragma unroll
            for (int nt = 0; nt < 2; ++nt)
#pragma unroll
                for (int r = 0; r < 4; ++r)
                    part[nt][r] += __shfl_xor(part[nt][r], msk);
        if (mrow == 0) {
#pragma unroll
            for (int nt = 0; nt < 2; ++nt) {
                const int nb = wv * 32 + nt * 16 + kg * 4;
                float4 o = make_float4(part[nt][0] + nb3[nb],     part[nt][1] + nb3[nb + 1],
                                       part[nt][2] + nb3[nb + 2], part[nt][3] + nb3[nb + 3]);
                *reinterpret_cast<float4*>(pre_out + (long)node * DIM + nb) = o;
            }
        }
    }
}

extern "C" void kernel_launch(void* const* d_in, const int* in_sizes, int n_in,
                              void* d_out, int out_size, void* d_ws, size_t ws_size,
                              hipStream_t stream) {
    const float* h   = (const float*)d_in[0];
    const float* e   = (const float*)d_in[1];
    const int*   ei  = (const int*)d_in[2];
    const float* aw1 = (const float*)d_in[3];
    const float* ab1 = (const float*)d_in[4];
    const float* aw2 = (const float*)d_in[5];
    const float* ab2 = (const float*)d_in[6];
    const float* aw3 = (const float*)d_in[7];
    const float* ab3 = (const float*)d_in[8];
    const float* nw1 = (const float*)d_in[9];
    const float* nb1 = (const float*)d_in[10];
    const float* nw2 = (const float*)d_in[11];
    const float* nb2 = (const float*)d_in[12];
    const float* nw3 = (const float*)d_in[13];
    const float* nb3 = (const float*)d_in[14];
    const float* thw = (const float*)d_in[15];
    float* out = (float*)d_out;
    __bf16* wp = (__bf16*)d_ws;
    float* yhi = (float*)((char*)d_ws + YHI_BYTE_OFF);

    // all-weight repack (f32 -> bf16 MFMA-fragment order), one launch
    repack_all<<<TOT_TILES * 2, 256, 0, stream>>>(aw1, aw2, nw1, nw2, nw3, thw, wp);

    const int nblk = (N_NODES + 63) / 64;
    // yhi = h @ att_w1[0:128,:] + ab1   (hi part of att layer 1, per node)
    mm128<<<nblk, 512, 0, stream>>>(h, yhi, wp + OFF_AW1, ab1);

    gnn_fused<<<N_NODES, 256, 0, stream>>>(h, e, ei, yhi, ab2, aw3, ab3,
                                           nb1, nb2, nb3, wp, out);
    // out = pre @ to_h_w (in-place)
    mm128<<<nblk, 512, 0, stream>>>(out, out, wp + OFF_TH, nullptr);
}